// Round 1
// baseline (279.154 us; speedup 1.0000x reference)
//
#include <hip/hip_runtime.h>

#define BATCH 128
#define M 259
#define D 512
#define T 256
#define NM (BATCH * M)          // 33152
#define OUTHALF (BATCH * T * D) // 16777216

// ws float layout: na[NM] | nb[NM] | wcol[NM] | wrow[NM]   (530 KB total)

// ---------------- Kernel 1: norms + zero accumulators ----------------
__global__ void k_norms(const float* __restrict__ x1, const float* __restrict__ x2,
                        float* __restrict__ ws) {
    int wave = blockIdx.x * 4 + (threadIdx.x >> 6);
    int lane = threadIdx.x & 63;
    if (wave >= NM) return;
    const float4* p1 = (const float4*)(x1 + (size_t)wave * D);
    const float4* p2 = (const float4*)(x2 + (size_t)wave * D);
    float s1 = 0.f, s2 = 0.f;
#pragma unroll
    for (int q = 0; q < 2; ++q) {
        float4 v = p1[lane + q * 64];
        s1 += v.x * v.x + v.y * v.y + v.z * v.z + v.w * v.w;
        float4 w = p2[lane + q * 64];
        s2 += w.x * w.x + w.y * w.y + w.z * w.z + w.w * w.w;
    }
#pragma unroll
    for (int off = 32; off > 0; off >>= 1) {
        s1 += __shfl_xor(s1, off);
        s2 += __shfl_xor(s2, off);
    }
    if (lane == 0) {
        ws[wave]          = s1;   // na
        ws[NM + wave]     = s2;   // nb
        ws[2 * NM + wave] = 0.f;  // wcol accumulator
        ws[3 * NM + wave] = 0.f;  // wrow accumulator
    }
}

// ---------------- Kernel 2: tiled pairwise GEMM + fused A + row/col sums ----
#define BT 64
#define BK 32
#define NT 5  // ceil(259/64)

__launch_bounds__(64)
__global__ void k_pairs(const float* __restrict__ x1, const float* __restrict__ x2,
                        float* __restrict__ ws) {
    __shared__ float As[BK][BT];
    __shared__ float Bs[BK][BT];
    int bid = blockIdx.x;
    int tj = bid % NT;
    int ti = (bid / NT) % NT;
    int b  = bid / (NT * NT);
    int i0 = ti * BT, j0 = tj * BT;
    int t  = threadIdx.x;
    int tx = t & 7, ty = t >> 3;

    const float* Abase = x1 + (size_t)b * M * D;
    const float* Bbase = x2 + (size_t)b * M * D;

    // each lane stages one row of each tile (clamped; invalid rows masked later)
    int ra = min(i0 + t, M - 1);
    int rb = min(j0 + t, M - 1);
    const float* arow = Abase + (size_t)ra * D;
    const float* brow = Bbase + (size_t)rb * D;

    float acc[8][8];
#pragma unroll
    for (int r = 0; r < 8; ++r)
#pragma unroll
        for (int c = 0; c < 8; ++c) acc[r][c] = 0.f;

    for (int k0 = 0; k0 < D; k0 += BK) {
        __syncthreads();
#pragma unroll
        for (int e = 0; e < 8; ++e) {
            float4 va = *(const float4*)(arow + k0 + e * 4);
            float4 vb = *(const float4*)(brow + k0 + e * 4);
            As[e * 4 + 0][t] = va.x; As[e * 4 + 1][t] = va.y;
            As[e * 4 + 2][t] = va.z; As[e * 4 + 3][t] = va.w;
            Bs[e * 4 + 0][t] = vb.x; Bs[e * 4 + 1][t] = vb.y;
            Bs[e * 4 + 2][t] = vb.z; Bs[e * 4 + 3][t] = vb.w;
        }
        __syncthreads();
#pragma unroll
        for (int k = 0; k < BK; ++k) {
            float4 a0 = *(const float4*)&As[k][ty * 8];
            float4 a1 = *(const float4*)&As[k][ty * 8 + 4];
            float4 b0 = *(const float4*)&Bs[k][tx * 8];
            float4 b1 = *(const float4*)&Bs[k][tx * 8 + 4];
            float avv[8] = {a0.x, a0.y, a0.z, a0.w, a1.x, a1.y, a1.z, a1.w};
            float bvv[8] = {b0.x, b0.y, b0.z, b0.w, b1.x, b1.y, b1.z, b1.w};
#pragma unroll
            for (int r = 0; r < 8; ++r)
#pragma unroll
                for (int c = 0; c < 8; ++c)
                    acc[r][c] = fmaf(avv[r], bvv[c], acc[r][c]);
        }
    }

    // epilogue: A_ij = 1/(1+sqrt(max(na+nb-2g,0))), masked; partial row/col sums
    int b_off = b * M;
    float na_[8], nb_[8];
#pragma unroll
    for (int r = 0; r < 8; ++r) {
        int i = i0 + ty * 8 + r;
        na_[r] = (i < M) ? ws[b_off + i] : 0.f;
    }
#pragma unroll
    for (int c = 0; c < 8; ++c) {
        int j = j0 + tx * 8 + c;
        nb_[c] = (j < M) ? ws[NM + b_off + j] : 0.f;
    }
    float rowsum[8], colsum[8];
#pragma unroll
    for (int r = 0; r < 8; ++r) rowsum[r] = 0.f;
#pragma unroll
    for (int c = 0; c < 8; ++c) colsum[c] = 0.f;
#pragma unroll
    for (int r = 0; r < 8; ++r) {
        int i = i0 + ty * 8 + r;
#pragma unroll
        for (int c = 0; c < 8; ++c) {
            int j = j0 + tx * 8 + c;
            float av = 0.f;
            if (i < M && j < M) {
                float sq = na_[r] + nb_[c] - 2.f * acc[r][c];
                float dist = sqrtf(fmaxf(sq, 0.f));
                av = 1.f / (1.f + dist);
            }
            rowsum[r] += av;
            colsum[c] += av;
        }
    }
    // reduce rowsum across tx lanes (xor 1,2,4); lane tx==0 commits
#pragma unroll
    for (int r = 0; r < 8; ++r) {
        float v = rowsum[r];
        v += __shfl_xor(v, 1); v += __shfl_xor(v, 2); v += __shfl_xor(v, 4);
        if (tx == 0) {
            int i = i0 + ty * 8 + r;
            if (i < M) atomicAdd(&ws[3 * NM + b_off + i], v);  // wrow
        }
    }
    // reduce colsum across ty lanes (xor 8,16,32); lane ty==0 commits
#pragma unroll
    for (int c = 0; c < 8; ++c) {
        float v = colsum[c];
        v += __shfl_xor(v, 8); v += __shfl_xor(v, 16); v += __shfl_xor(v, 32);
        if (ty == 0) {
            int j = j0 + tx * 8 + c;
            if (j < M) atomicAdd(&ws[2 * NM + b_off + j], v);  // wcol
        }
    }
}

// ---------------- Kernel 3: sliding-window weighted sum -> outputs ----------
__global__ void k_out(const float* __restrict__ x1, const float* __restrict__ x2,
                      const float* __restrict__ ws, float* __restrict__ out) {
    int bid   = blockIdx.x;
    int which = bid & 1;         // 0 -> w1 (a, wcol), 1 -> w2 (b, wrow)
    int dh    = (bid >> 1) & 1;  // d half
    int tc    = (bid >> 2) & 3;  // t chunk of 64
    int b     = bid >> 4;
    int d     = dh * 256 + threadIdx.x;
    const float* src  = which ? x2 : x1;
    const float* w    = ws + (which ? 3 * NM : 2 * NM) + b * M;
    const float* rows = src + (size_t)b * M * D + d;
    float* o = out + (size_t)which * OUTHALF + ((size_t)b * T + tc * 64) * D + d;
    int t0 = tc * 64;
    float v0 = rows[(size_t)(t0 + 0) * D];
    float v1 = rows[(size_t)(t0 + 1) * D];
    float v2 = rows[(size_t)(t0 + 2) * D];
    float s0 = w[t0 + 0], s1 = w[t0 + 1], s2 = w[t0 + 2];
    for (int tt = 0; tt < 64; ++tt) {
        int tg = t0 + tt;
        float v3 = rows[(size_t)(tg + 3) * D];
        float s3 = w[tg + 3];
        o[(size_t)tt * D] = s0 * v0 + s1 * v1 + s2 * v2 + s3 * v3;
        v0 = v1; v1 = v2; v2 = v3;
        s0 = s1; s1 = s2; s2 = s3;
    }
}

extern "C" void kernel_launch(void* const* d_in, const int* in_sizes, int n_in,
                              void* d_out, int out_size, void* d_ws, size_t ws_size,
                              hipStream_t stream) {
    const float* x1 = (const float*)d_in[0];
    const float* x2 = (const float*)d_in[1];
    float* out = (float*)d_out;
    float* ws  = (float*)d_ws;

    k_norms<<<NM / 4, 256, 0, stream>>>(x1, x2, ws);              // 8288 blocks
    k_pairs<<<BATCH * NT * NT, 64, 0, stream>>>(x1, x2, ws);      // 3200 blocks
    k_out<<<BATCH * 16, 256, 0, stream>>>(x1, x2, ws, out);       // 2048 blocks
}

// Round 2
// 112.581 us; speedup vs baseline: 2.4796x; 2.4796x over previous
//
#include <hip/hip_runtime.h>

#define BATCH 128
#define M 259
#define D 512
#define T 256
#define NM (BATCH * M)          // 33152
#define OUTHALF (BATCH * T * D)

typedef __bf16 bf16;
typedef __bf16 bf16x4 __attribute__((ext_vector_type(4)));
typedef __bf16 bf16x8 __attribute__((ext_vector_type(8)));
typedef float f32x4 __attribute__((ext_vector_type(4)));

// ws float layout: na[NM] | nb[NM] | wcol[NM] | wrow[NM]

// ---------------- Kernel 1: norms + zero accumulators ----------------
__global__ void k_norms(const float* __restrict__ x1, const float* __restrict__ x2,
                        float* __restrict__ ws) {
    int wave = blockIdx.x * 4 + (threadIdx.x >> 6);
    int lane = threadIdx.x & 63;
    if (wave >= NM) return;
    const float4* p1 = (const float4*)(x1 + (size_t)wave * D);
    const float4* p2 = (const float4*)(x2 + (size_t)wave * D);
    float s1 = 0.f, s2 = 0.f;
#pragma unroll
    for (int q = 0; q < 2; ++q) {
        float4 v = p1[lane + q * 64];
        s1 += v.x * v.x + v.y * v.y + v.z * v.z + v.w * v.w;
        float4 w = p2[lane + q * 64];
        s2 += w.x * w.x + w.y * w.y + w.z * w.z + w.w * w.w;
    }
#pragma unroll
    for (int off = 32; off > 0; off >>= 1) {
        s1 += __shfl_xor(s1, off);
        s2 += __shfl_xor(s2, off);
    }
    if (lane == 0) {
        ws[wave]          = s1;
        ws[NM + wave]     = s2;
        ws[2 * NM + wave] = 0.f;
        ws[3 * NM + wave] = 0.f;
    }
}

// ---------------- Kernel 2: bf16 MFMA pairwise + fused sums ----------------
#define BT 96
#define BK 64
#define NTL 3   // tiles per dim (3*96 = 288 >= 259)

__launch_bounds__(256)
__global__ void k_pairs(const float* __restrict__ x1, const float* __restrict__ x2,
                        float* __restrict__ ws) {
    __shared__ __align__(16) bf16 As[BT * BK];
    __shared__ __align__(16) bf16 Bs[BT * BK];

    // XCD-aware bijective swizzle: 1152 blocks = 8 * 144
    int s   = blockIdx.x;
    int bid = (s & 7) * 144 + (s >> 3);
    int b   = bid / 9;
    int ti  = (bid % 9) / 3;
    int tj  = bid % 3;
    int i0  = ti * BT, j0 = tj * BT;

    int t    = threadIdx.x;
    int lane = t & 63;
    int w    = t >> 6;
    int wm   = w >> 1, wn = w & 1;
    int iw   = i0 + wm * 48;   // wave's first a-row
    int jw   = j0 + wn * 48;   // wave's first b-row

    const float* Ab = x1 + (size_t)b * M * D;
    const float* Bb = x2 + (size_t)b * M * D;

    // --- staging addressing: 6 passes of 16 rows x 64 cols, 1 float4/thread/pass
    const float* pa[6];
    const float* pb[6];
    int c4 = (t & 15) * 4;
#pragma unroll
    for (int p = 0; p < 6; ++p) {
        int ra = min(i0 + p * 16 + (t >> 4), M - 1);
        int rb = min(j0 + p * 16 + (t >> 4), M - 1);
        pa[p] = Ab + (size_t)ra * D + c4;
        pb[p] = Bb + (size_t)rb * D + c4;
    }
    int wslot   = (t & 15) >> 1;    // 16B slot within row (0..7)
    int wwithin = (t & 1) * 4;      // element offset within slot
    int wr_off[6];
#pragma unroll
    for (int p = 0; p < 6; ++p) {
        int row = p * 16 + (t >> 4);
        wr_off[p] = row * BK + ((wslot ^ (row & 7)) << 3) + wwithin;
    }

    // --- fragment read offsets (element units), swizzle-matched
    int a_off[3][2], b_off[3][2];
#pragma unroll
    for (int fm = 0; fm < 3; ++fm) {
        int rowa = wm * 48 + fm * 16 + (lane & 15);
        int rowb = wn * 48 + fm * 16 + (lane & 15);
#pragma unroll
        for (int kk = 0; kk < 2; ++kk) {
            int slot = kk * 4 + (lane >> 4);
            a_off[fm][kk] = rowa * BK + ((slot ^ (rowa & 7)) << 3);
            b_off[fm][kk] = rowb * BK + ((slot ^ (rowb & 7)) << 3);
        }
    }

    f32x4 acc[3][3];
#pragma unroll
    for (int fm = 0; fm < 3; ++fm)
#pragma unroll
        for (int fn = 0; fn < 3; ++fn) acc[fm][fn] = (f32x4)0.f;

    for (int k0 = 0; k0 < D; k0 += BK) {
        float4 va[6], vb[6];
#pragma unroll
        for (int p = 0; p < 6; ++p) {
            va[p] = *(const float4*)(pa[p] + k0);
            vb[p] = *(const float4*)(pb[p] + k0);
        }
        __syncthreads();
#pragma unroll
        for (int p = 0; p < 6; ++p) {
            bf16x4 ca = { (bf16)va[p].x, (bf16)va[p].y, (bf16)va[p].z, (bf16)va[p].w };
            bf16x4 cb = { (bf16)vb[p].x, (bf16)vb[p].y, (bf16)vb[p].z, (bf16)vb[p].w };
            *(bf16x4*)&As[wr_off[p]] = ca;
            *(bf16x4*)&Bs[wr_off[p]] = cb;
        }
        __syncthreads();
#pragma unroll
        for (int kk = 0; kk < 2; ++kk) {
            bf16x8 af[3], bfr[3];
#pragma unroll
            for (int fm = 0; fm < 3; ++fm) af[fm]  = *(const bf16x8*)&As[a_off[fm][kk]];
#pragma unroll
            for (int fn = 0; fn < 3; ++fn) bfr[fn] = *(const bf16x8*)&Bs[b_off[fn][kk]];
#pragma unroll
            for (int fm = 0; fm < 3; ++fm)
#pragma unroll
                for (int fn = 0; fn < 3; ++fn)
                    acc[fm][fn] = __builtin_amdgcn_mfma_f32_16x16x32_bf16(
                        af[fm], bfr[fn], acc[fm][fn], 0, 0, 0);
        }
    }

    // --- epilogue: A_ij = 1/(1+dist), masked; row/col partial sums
    int b_off_w = b * M;
    float na_[3][4], nb_[3];
#pragma unroll
    for (int fm = 0; fm < 3; ++fm)
#pragma unroll
        for (int r = 0; r < 4; ++r) {
            int i = iw + fm * 16 + (lane >> 4) * 4 + r;
            na_[fm][r] = (i < M) ? ws[b_off_w + i] : 0.f;
        }
#pragma unroll
    for (int fn = 0; fn < 3; ++fn) {
        int j = jw + fn * 16 + (lane & 15);
        nb_[fn] = (j < M) ? ws[NM + b_off_w + j] : 0.f;
    }

    float rs[3][4];   // [fm][reg] — partial sums over j (this lane's cols)
    float cs[3];      // [fn]      — partial sums over i (this lane's rows)
#pragma unroll
    for (int fm = 0; fm < 3; ++fm)
#pragma unroll
        for (int r = 0; r < 4; ++r) rs[fm][r] = 0.f;
#pragma unroll
    for (int fn = 0; fn < 3; ++fn) cs[fn] = 0.f;

#pragma unroll
    for (int fm = 0; fm < 3; ++fm) {
#pragma unroll
        for (int fn = 0; fn < 3; ++fn) {
#pragma unroll
            for (int r = 0; r < 4; ++r) {
                int i = iw + fm * 16 + (lane >> 4) * 4 + r;
                int j = jw + fn * 16 + (lane & 15);
                float av = 0.f;
                if (i < M && j < M) {
                    float sq   = na_[fm][r] + nb_[fn] - 2.f * acc[fm][fn][r];
                    float dist = sqrtf(fmaxf(sq, 0.f));
                    av = 1.f / (1.f + dist);
                }
                rs[fm][r] += av;
                cs[fn]    += av;
            }
        }
    }

    // rows (sum over j) -> wrow (ws[3*NM..]); reduce across lane&15
#pragma unroll
    for (int fm = 0; fm < 3; ++fm)
#pragma unroll
        for (int r = 0; r < 4; ++r) {
            float v = rs[fm][r];
            v += __shfl_xor(v, 1); v += __shfl_xor(v, 2);
            v += __shfl_xor(v, 4); v += __shfl_xor(v, 8);
            int i = iw + fm * 16 + (lane >> 4) * 4 + r;
            if ((lane & 15) == 0 && i < M) atomicAdd(&ws[3 * NM + b_off_w + i], v);
        }
    // cols (sum over i) -> wcol (ws[2*NM..]); reduce across lane>>4
#pragma unroll
    for (int fn = 0; fn < 3; ++fn) {
        float v = cs[fn];
        v += __shfl_xor(v, 16); v += __shfl_xor(v, 32);
        int j = jw + fn * 16 + (lane & 15);
        if ((lane >> 4) == 0 && j < M) atomicAdd(&ws[2 * NM + b_off_w + j], v);
    }
}

// ---------------- Kernel 3: sliding-window weighted sum -> outputs ----------
__global__ void k_out(const float* __restrict__ x1, const float* __restrict__ x2,
                      const float* __restrict__ ws, float* __restrict__ out) {
    int bid   = blockIdx.x;
    int which = bid & 1;
    int dh    = (bid >> 1) & 1;
    int tc    = (bid >> 2) & 3;
    int b     = bid >> 4;
    int d     = dh * 256 + threadIdx.x;
    const float* src  = which ? x2 : x1;
    const float* w    = ws + (which ? 3 * NM : 2 * NM) + b * M;
    const float* rows = src + (size_t)b * M * D + d;
    float* o = out + (size_t)which * OUTHALF + ((size_t)b * T + tc * 64) * D + d;
    int t0 = tc * 64;
    float v0 = rows[(size_t)(t0 + 0) * D];
    float v1 = rows[(size_t)(t0 + 1) * D];
    float v2 = rows[(size_t)(t0 + 2) * D];
    float s0 = w[t0 + 0], s1 = w[t0 + 1], s2 = w[t0 + 2];
    for (int tt = 0; tt < 64; ++tt) {
        int tg = t0 + tt;
        float v3 = rows[(size_t)(tg + 3) * D];
        float s3 = w[tg + 3];
        o[(size_t)tt * D] = s0 * v0 + s1 * v1 + s2 * v2 + s3 * v3;
        v0 = v1; v1 = v2; v2 = v3;
        s0 = s1; s1 = s2; s2 = s3;
    }
}

extern "C" void kernel_launch(void* const* d_in, const int* in_sizes, int n_in,
                              void* d_out, int out_size, void* d_ws, size_t ws_size,
                              hipStream_t stream) {
    const float* x1 = (const float*)d_in[0];
    const float* x2 = (const float*)d_in[1];
    float* out = (float*)d_out;
    float* ws  = (float*)d_ws;

    k_norms<<<NM / 4, 256, 0, stream>>>(x1, x2, ws);                      // 8288 blocks
    k_pairs<<<BATCH * NTL * NTL, 256, 0, stream>>>(x1, x2, ws);           // 1152 blocks
    k_out<<<BATCH * 16, 256, 0, stream>>>(x1, x2, ws, out);               // 2048 blocks
}